// Round 14
// baseline (104.076 us; speedup 1.0000x reference)
//
#include <hip/hip_runtime.h>
#include <math.h>

#define NN 65536
#define NG 64
#define NPG 1024
#define HID 128
#define KNN 16
#define BINF 1e30f
#define BWS 272            // padded LDS row stride (bytes): 17*16B -> dRow=4 => dBank=16

typedef unsigned long long ull;
typedef _Float16 f16;
typedef _Float16 f16x8 __attribute__((ext_vector_type(8)));
typedef float f32x4 __attribute__((ext_vector_type(4)));

__device__ __forceinline__ f16x8 vmax8(f16x8 a, f16x8 b) {
    return __builtin_elementwise_max(a, b);
}

// ---------------------------------------------------------------- kNN sort + weight prep
__global__ __launch_bounds__(1024) void k_topk(
    const float* __restrict__ x, int* __restrict__ sidxg,
    short* __restrict__ nbroff,
    const float* __restrict__ ig_lw, const float* __restrict__ ig_gw,
    const float* __restrict__ c1_w, const float* __restrict__ c2_w,
    f16* __restrict__ gfrag, f16* __restrict__ f1, f16* __restrict__ f2) {
    __shared__ ull key[1024];
    __shared__ float st[1024];
    __shared__ int sidx[1024];
    int g = blockIdx.x;
    if (g >= NG) {
        int gid = (g - NG) * 1024 + threadIdx.x;   // [0, 81920)
        if (gid < 16384) {
            int i = gid & 7, lane = (gid >> 3) & 63, nt = (gid >> 9) & 7;
            int kt = (gid >> 12) & 1, mat = gid >> 13;
            int k = kt * 32 + ((lane >> 4) << 3) + i;
            int c = nt * 16 + (lane & 15);
            float v = 0.0f;
            if (k < 48) v = (mat ? ig_gw : ig_lw)[k * 128 + c];
            gfrag[gid] = (f16)v;
        } else {
            int g2 = gid - 16384;
            int buf = g2 >> 15;
            int rem = g2 & 32767;
            int mat = rem >> 14;
            int r2 = rem & 16383;
            int i = r2 & 7, lane = (r2 >> 3) & 63, nt = (r2 >> 9) & 7, kt = (r2 >> 12) & 3;
            int k = kt * 32 + ((lane >> 4) << 3) + i;
            int c = nt * 16 + (lane & 15);
            const float* cw = buf ? c2_w : c1_w;
            float top = cw[k * 128 + c];
            float bot = cw[(128 + k) * 128 + c];
            float v = mat ? bot : (top - bot);
            (buf ? f2 : f1)[rem] = (f16)v;
        }
        return;
    }
    int i = threadIdx.x;
    float t = x[(size_t)(g * NPG + i) * 17];
    unsigned ub = __float_as_uint(t);
    ub = (ub & 0x80000000u) ? ~ub : (ub | 0x80000000u);   // order-preserving map
    ull kk = ((ull)ub << 32) | (unsigned)i;

    for (int k = 2; k <= 1024; k <<= 1) {
        for (int j = k >> 1; j > 0; j >>= 1) {
            ull pv;
            if (j >= 64) {
                key[i] = kk;
                __syncthreads();
                pv = key[i ^ j];
                __syncthreads();
            } else {
                pv = __shfl_xor(kk, j, 64);
            }
            bool up = ((i & k) == 0);
            bool low = ((i & j) == 0);
            ull mn = kk < pv ? kk : pv;
            ull mx = kk < pv ? pv : kk;
            kk = (up == low) ? mn : mx;
        }
    }
    int oi = (int)(kk & 0xffffffffu);
    st[i] = x[(size_t)(g * NPG + oi) * 17];
    sidx[i] = oi;
    sidxg[g * NPG + i] = g * NPG + oi;
    __syncthreads();

    // two-pointer merge in rank space; offsets pre-scaled by LDS row stride
    float tt = st[i];
    int L = i - 1, R = i + 1;
    short* out = nbroff + (size_t)(g * NPG + i) * KNN;
#pragma unroll
    for (int q = 0; q < KNN; q++) {
        float dl = (L >= 0)   ? (tt - st[L]) : BINF;
        float dr = (R < NPG) ? (st[R] - tt) : BINF;
        bool left;
        if (dl < dr) left = true;
        else if (dr < dl) left = false;
        else left = (sidx[L] < sidx[R]);   // tie: lower original index (lax.top_k)
        int jr;
        if (left) { jr = L; L--; }
        else      { jr = R; R++; }
        out[q] = (short)((jr - i) * BWS);
    }
}

// ---------------------------------------------------------------- fused GLU + conv1
__global__ __launch_bounds__(256) void k_fuse1(
    const float* __restrict__ x, const float* __restrict__ te_w,
    const float* __restrict__ te_b, const f16x8* __restrict__ gfrag,
    const float* __restrict__ bl, const float* __restrict__ bg,
    const int* __restrict__ sidxg, const f16x8* __restrict__ wfrag,
    const float* __restrict__ cb, f16* __restrict__ A, f16* __restrict__ B) {
    __shared__ f16x8 XL[4 * 2 * 64];          // Z fragments [mf][kt][lane]
    __shared__ f16 ht[64 * 128];              // XOR-swizzled H tile
    int tid = threadIdx.x;
    int r0 = blockIdx.x * 64;
#pragma unroll
    for (int p = 0; p < 2; p++) {
        int idx = tid + p * 256;              // [0,512)
        int row = idx >> 3, kq = idx & 7;
        int node = sidxg[r0 + row];
        f16x8 h;
        if (kq < 2) {
            const float* xr = x + (size_t)node * 17 + 1 + kq * 8;
#pragma unroll
            for (int i = 0; i < 8; i++) h[i] = (f16)xr[i];
        } else if (kq < 6) {
            float t = x[(size_t)node * 17];
            int j0 = (kq - 2) * 8;
#pragma unroll
            for (int i = 0; i < 8; i++) h[i] = (f16)fmaf(t, te_w[j0 + i], te_b[j0 + i]);
        } else {
#pragma unroll
            for (int i = 0; i < 8; i++) h[i] = (f16)0.0f;
        }
        int mf = row >> 4, kt = kq >> 2, lane = ((kq & 3) << 4) | (row & 15);
        XL[(mf * 2 + kt) * 64 + lane] = h;
    }
    __syncthreads();
    int w = tid >> 6, lane = tid & 63;
    f32x4 acc[2][2][4];
#pragma unroll
    for (int o = 0; o < 2; o++)
#pragma unroll
        for (int j = 0; j < 2; j++)
#pragma unroll
            for (int mf = 0; mf < 4; mf++) acc[o][j][mf] = (f32x4){0.f, 0.f, 0.f, 0.f};
#pragma unroll 1
    for (int kt = 0; kt < 2; kt++) {
        f16x8 wf0[2], wf1[2], xa[4];
#pragma unroll
        for (int j = 0; j < 2; j++) {
            wf0[j] = gfrag[((0 * 2 + kt) * 8 + (w * 2 + j)) * 64 + lane];
            wf1[j] = gfrag[((1 * 2 + kt) * 8 + (w * 2 + j)) * 64 + lane];
        }
#pragma unroll
        for (int mf = 0; mf < 4; mf++) xa[mf] = XL[(mf * 2 + kt) * 64 + lane];
#pragma unroll
        for (int mf = 0; mf < 4; mf++)
#pragma unroll
            for (int j = 0; j < 2; j++) {
                acc[0][j][mf] = __builtin_amdgcn_mfma_f32_16x16x32_f16(xa[mf], wf0[j], acc[0][j][mf], 0, 0, 0);
                acc[1][j][mf] = __builtin_amdgcn_mfma_f32_16x16x32_f16(xa[mf], wf1[j], acc[1][j][mf], 0, 0, 0);
            }
    }
    // GLU epilogue -> swizzled LDS tile
#pragma unroll
    for (int j = 0; j < 2; j++) {
        int col = w * 32 + j * 16 + (lane & 15);
        float bbl = bl[col], bbg = bg[col];
#pragma unroll
        for (int mf = 0; mf < 4; mf++) {
            int rloc = mf * 16 + ((lane >> 4) << 2);
#pragma unroll
            for (int q = 0; q < 4; q++) {
                float lin = acc[0][j][mf][q] + bbl;
                float gat = acc[1][j][mf][q] + bbg;
                int row = rloc + q;
                ht[(row * 128 + col) ^ ((row & 7) << 3)] = (f16)(lin / (1.0f + expf(-gat)));
            }
        }
    }
    __syncthreads();
    // conv1 dual GEMM from ht
#pragma unroll
    for (int o = 0; o < 2; o++)
#pragma unroll
        for (int j = 0; j < 2; j++)
#pragma unroll
            for (int mf = 0; mf < 4; mf++) acc[o][j][mf] = (f32x4){0.f, 0.f, 0.f, 0.f};
    int row16 = lane & 15, kslot = lane >> 4;
    int swz = (row16 & 7) << 3;
#pragma unroll 1
    for (int kt = 0; kt < 4; kt++) {
        f16x8 wf0[2], wf1[2], xa[4];
#pragma unroll
        for (int j = 0; j < 2; j++) {
            wf0[j] = wfrag[((0 * 4 + kt) * 8 + (w * 2 + j)) * 64 + lane];
            wf1[j] = wfrag[((1 * 4 + kt) * 8 + (w * 2 + j)) * 64 + lane];
        }
#pragma unroll
        for (int mf = 0; mf < 4; mf++)
            xa[mf] = *(const f16x8*)&ht[((mf * 16 + row16) * 128 + kt * 32 + kslot * 8) ^ swz];
#pragma unroll
        for (int mf = 0; mf < 4; mf++)
#pragma unroll
            for (int j = 0; j < 2; j++) {
                acc[0][j][mf] = __builtin_amdgcn_mfma_f32_16x16x32_f16(xa[mf], wf0[j], acc[0][j][mf], 0, 0, 0);
                acc[1][j][mf] = __builtin_amdgcn_mfma_f32_16x16x32_f16(xa[mf], wf1[j], acc[1][j][mf], 0, 0, 0);
            }
    }
#pragma unroll
    for (int j = 0; j < 2; j++) {
        int col = w * 32 + j * 16 + (lane & 15);
        float bias = cb[col];
#pragma unroll
        for (int mf = 0; mf < 4; mf++) {
            int rbase = r0 + mf * 16 + ((lane >> 4) << 2);
#pragma unroll
            for (int q = 0; q < 4; q++) {
                A[(size_t)(rbase + q) * 128 + col] = (f16)(acc[0][j][mf][q] + bias);
                B[(size_t)(rbase + q) * 128 + col] = (f16)acc[1][j][mf][q];
            }
        }
    }
}

// ---------------------------------------------------------------- conv2 + gather2 + pools
// 512 threads / 8 waves; LDS 79.9KB -> 2 blocks/CU = 16 waves/CU.
// Branch-free gather; A1 prefetched pre-barrier; grouped tree-max.
__global__ __launch_bounds__(512) void k_megac2(
    const f16* __restrict__ A1, const f16* __restrict__ B1,
    const short* __restrict__ nbroff, const f16x8* __restrict__ wfrag,
    const float* __restrict__ cb,
    float* __restrict__ partM1, float* __restrict__ partS1,
    float* __restrict__ partM2, float* __restrict__ partS2) {
    __shared__ char SM[79872];
    char* bw  = SM;                            // B1 window: 128 rows x BWS
    char* b2  = SM;                            // B2: 96 rows x BWS (aliases bw post-gather1)
    f16*  x1t = (f16*)(SM + 34816);            // 96x128 f16 swizzled (24576 B)
    char* a2  = SM + 59392;                    // A2: 64 rows x BWS (17408 B)
    float* redM1 = (float*)(SM + 59392);       // 8x128 f32, aliases a2 (pre-epilogue)
    float* redS1 = (float*)(SM + 63488);
    float* redM2 = (float*)(SM + 34816);       // 8x128 f32, aliases x1t (post-GEMM)
    float* redS2 = (float*)(SM + 38912);
    short* nbrL = (short*)(SM + 76800);        // 96 rows x 16 shorts (3072 B)

    int tid = threadIdx.x;
    int bx = blockIdx.x;
    int r0 = bx * 64;
    int r0loc = (bx & 15) * 64;
    int gbase = r0 - r0loc;                    // graph base row

    int w = tid >> 6, lane = tid & 63;         // w in [0,8)
    int rquad = lane >> 4;
    int c0 = (lane & 15) * 8;

    // ---- prefetch A1 octets for this thread's 3 gather1 rows (clamped; overlaps staging)
    f16x8 av0, av1, av2;
    {
#pragma unroll
        for (int rr = 0; rr < 3; rr++) {
            int row = w * 12 + rr * 4 + rquad;
            int gl = r0loc - 16 + row;
            int glc = gl < 0 ? 0 : (gl > NPG - 1 ? NPG - 1 : gl);
            f16x8 v = *(const f16x8*)(A1 + (size_t)(gbase + glc) * 128 + c0);
            if (rr == 0) av0 = v; else if (rr == 1) av1 = v; else av2 = v;
        }
    }

    // ---- stage B1 window ranks [r0loc-32, r0loc+96): 2048 octets, 4 passes
#pragma unroll
    for (int p = 0; p < 4; p++) {
        int idx = tid + p * 512;               // [0,2048)
        int row = idx >> 4, kq = idx & 15;
        int gl = r0loc - 32 + row;
        f16x8 v;
#pragma unroll
        for (int i = 0; i < 8; i++) v[i] = (f16)0.0f;
        if (gl >= 0 && gl < NPG)
            v = *(const f16x8*)(B1 + (size_t)(gbase + gl) * 128 + kq * 8);
        *(f16x8*)(bw + row * BWS + kq * 16) = v;
    }
    // ---- stage neighbor offsets for ranks [r0loc-16, r0loc+80)
    if (tid < 192) {
        int row = tid >> 1, half = tid & 1;
        int gl = r0loc - 16 + row;
        int4 v = {0, 0, 0, 0};
        if (gl >= 0 && gl < NPG)
            v = ((const int4*)(nbroff + (size_t)(gbase + gl) * KNN))[half];
        ((int4*)nbrL)[tid] = v;
    }
    __syncthreads();

    // ---- gather1: x1 for 96 halo rows (12 rows/wave); pool interior [16,80)
    f16x8 pmv;
    float ps[8];
#pragma unroll
    for (int i = 0; i < 8; i++) { pmv[i] = (f16)(-INFINITY); ps[i] = 0.f; }
    // preload offset vectors for this thread's 3 rows (LDS, issue-independent)
    short ow0[16], ow1[16], ow2[16];
    {
        int row0 = w * 12 + 0 * 4 + rquad;
        int row1 = w * 12 + 1 * 4 + rquad;
        int row2 = w * 12 + 2 * 4 + rquad;
        *(int4*)&ow0[0] = ((const int4*)nbrL)[row0 * 2];
        *(int4*)&ow0[8] = ((const int4*)nbrL)[row0 * 2 + 1];
        *(int4*)&ow1[0] = ((const int4*)nbrL)[row1 * 2];
        *(int4*)&ow1[8] = ((const int4*)nbrL)[row1 * 2 + 1];
        *(int4*)&ow2[0] = ((const int4*)nbrL)[row2 * 2];
        *(int4*)&ow2[8] = ((const int4*)nbrL)[row2 * 2 + 1];
    }
    const f16x8 z = {(f16)0, (f16)0, (f16)0, (f16)0, (f16)0, (f16)0, (f16)0, (f16)0};
#pragma unroll
    for (int rr = 0; rr < 3; rr++) {
        const short* ow = (rr == 0) ? ow0 : (rr == 1) ? ow1 : ow2;
        f16x8 av = (rr == 0) ? av0 : (rr == 1) ? av1 : av2;
        int row = w * 12 + rr * 4 + rquad;     // [0,96)
        int gl = r0loc - 16 + row;
        bool valid = (gl >= 0) && (gl < NPG);
        const char* base = bw + (row + 16) * BWS + c0 * 2;
        // grouped tree-max: 4 groups of 4, depth ~6
        f16x8 m;
        {
            f16x8 b0 = *(const f16x8*)(base + (int)ow[0]);
            f16x8 b1v = *(const f16x8*)(base + (int)ow[1]);
            f16x8 b2v = *(const f16x8*)(base + (int)ow[2]);
            f16x8 b3 = *(const f16x8*)(base + (int)ow[3]);
            m = vmax8(vmax8(b0, b1v), vmax8(b2v, b3));
        }
#pragma unroll
        for (int gq = 1; gq < 4; gq++) {
            f16x8 b0 = *(const f16x8*)(base + (int)ow[gq * 4 + 0]);
            f16x8 b1v = *(const f16x8*)(base + (int)ow[gq * 4 + 1]);
            f16x8 b2v = *(const f16x8*)(base + (int)ow[gq * 4 + 2]);
            f16x8 b3 = *(const f16x8*)(base + (int)ow[gq * 4 + 3]);
            m = vmax8(m, vmax8(vmax8(b0, b1v), vmax8(b2v, b3)));
        }
        f16x8 ou = vmax8(av + m, z);
        if (!valid) ou = z;
        if ((row >= 16) && (row < 80)) {
            pmv = vmax8(pmv, ou);
#pragma unroll
            for (int i = 0; i < 8; i++) ps[i] += (float)ou[i];
        }
        int idx = (row * 128 + c0) ^ ((row & 7) << 3);
        *(f16x8*)&x1t[idx] = ou;
    }
    // x1 pool reduce (red1 aliases a2 region; a2 not yet written)
    float pm[8];
#pragma unroll
    for (int i = 0; i < 8; i++) pm[i] = (float)pmv[i];
#pragma unroll
    for (int i = 0; i < 8; i++) {
        pm[i] = fmaxf(pm[i], __shfl_xor(pm[i], 16));
        pm[i] = fmaxf(pm[i], __shfl_xor(pm[i], 32));
        ps[i] += __shfl_xor(ps[i], 16);
        ps[i] += __shfl_xor(ps[i], 32);
    }
    if (rquad == 0) {
#pragma unroll
        for (int i = 0; i < 8; i++) {
            redM1[w * 128 + c0 + i] = pm[i];
            redS1[w * 128 + c0 + i] = ps[i];
        }
    }
    __syncthreads();
    if (tid < 128) {
        float M = -BINF, S = 0.f;
#pragma unroll
        for (int w2 = 0; w2 < 8; w2++) {
            M = fmaxf(M, redM1[w2 * 128 + tid]);
            S += redS1[w2 * 128 + tid];
        }
        partM1[(size_t)bx * 128 + tid] = M;
        partS1[(size_t)bx * 128 + tid] = S;
    }
    __syncthreads();                           // red1 consumed before a2 epilogue writes

    // ---- dual GEMM over 96 rows: each wave one 16-col N-frag
    f32x4 acc[2][6];                           // [out][mf]
#pragma unroll
    for (int o = 0; o < 2; o++)
#pragma unroll
        for (int mf = 0; mf < 6; mf++) acc[o][mf] = (f32x4){0.f, 0.f, 0.f, 0.f};
    int row16 = lane & 15, kslot = lane >> 4;
    int swz = (row16 & 7) << 3;
#pragma unroll 1
    for (int kt = 0; kt < 4; kt++) {
        f16x8 wf0, wf1, xa[6];
        wf0 = wfrag[((0 * 4 + kt) * 8 + w) * 64 + lane];
        wf1 = wfrag[((1 * 4 + kt) * 8 + w) * 64 + lane];
#pragma unroll
        for (int mf = 0; mf < 6; mf++)
            xa[mf] = *(const f16x8*)&x1t[((mf * 16 + row16) * 128 + kt * 32 + kslot * 8) ^ swz];
#pragma unroll
        for (int mf = 0; mf < 6; mf++) {
            acc[0][mf] = __builtin_amdgcn_mfma_f32_16x16x32_f16(xa[mf], wf0, acc[0][mf], 0, 0, 0);
            acc[1][mf] = __builtin_amdgcn_mfma_f32_16x16x32_f16(xa[mf], wf1, acc[1][mf], 0, 0, 0);
        }
    }
    // epilogue -> LDS (B2 all 96 rows; A2 interior 64 rows)
    {
        int col = w * 16 + (lane & 15);
        float bias = cb[col];
#pragma unroll
        for (int mf = 0; mf < 6; mf++) {
            int rloc = mf * 16 + ((lane >> 4) << 2);
#pragma unroll
            for (int q = 0; q < 4; q++) {
                int hrow = rloc + q;           // [0,96)
                *(f16*)(b2 + hrow * BWS + col * 2) = (f16)acc[1][mf][q];
                if (hrow >= 16 && hrow < 80)
                    *(f16*)(a2 + (hrow - 16) * BWS + col * 2) = (f16)(acc[0][mf][q] + bias);
            }
        }
    }
    __syncthreads();                           // GEMM x1t reads done; a2/b2 visible

    // ---- gather2 + pool (interior 64 rows, 8 rows/wave), all from LDS
#pragma unroll
    for (int i = 0; i < 8; i++) { pmv[i] = (f16)(-INFINITY); ps[i] = 0.f; }
    short og0[16], og1[16];
    {
        int rl0 = w * 8 + 0 * 4 + rquad;
        int rl1 = w * 8 + 1 * 4 + rquad;
        *(int4*)&og0[0] = ((const int4*)nbrL)[(rl0 + 16) * 2];
        *(int4*)&og0[8] = ((const int4*)nbrL)[(rl0 + 16) * 2 + 1];
        *(int4*)&og1[0] = ((const int4*)nbrL)[(rl1 + 16) * 2];
        *(int4*)&og1[8] = ((const int4*)nbrL)[(rl1 + 16) * 2 + 1];
    }
#pragma unroll
    for (int rr = 0; rr < 2; rr++) {
        const short* ow = (rr == 0) ? og0 : og1;
        int rl = w * 8 + rr * 4 + rquad;       // [0,64)
        f16x8 av = *(const f16x8*)(a2 + rl * BWS + c0 * 2);
        const char* base = b2 + (rl + 16) * BWS + c0 * 2;
        f16x8 m;
        {
            f16x8 b0 = *(const f16x8*)(base + (int)ow[0]);
            f16x8 b1v = *(const f16x8*)(base + (int)ow[1]);
            f16x8 b2v = *(const f16x8*)(base + (int)ow[2]);
            f16x8 b3 = *(const f16x8*)(base + (int)ow[3]);
            m = vmax8(vmax8(b0, b1v), vmax8(b2v, b3));
        }
#pragma unroll
        for (int gq = 1; gq < 4; gq++) {
            f16x8 b0 = *(const f16x8*)(base + (int)ow[gq * 4 + 0]);
            f16x8 b1v = *(const f16x8*)(base + (int)ow[gq * 4 + 1]);
            f16x8 b2v = *(const f16x8*)(base + (int)ow[gq * 4 + 2]);
            f16x8 b3 = *(const f16x8*)(base + (int)ow[gq * 4 + 3]);
            m = vmax8(m, vmax8(vmax8(b0, b1v), vmax8(b2v, b3)));
        }
        f16x8 v = vmax8(av + m, z);
        pmv = vmax8(pmv, v);
#pragma unroll
        for (int i = 0; i < 8; i++) ps[i] += (float)v[i];
    }
#pragma unroll
    for (int i = 0; i < 8; i++) pm[i] = (float)pmv[i];
#pragma unroll
    for (int i = 0; i < 8; i++) {
        pm[i] = fmaxf(pm[i], __shfl_xor(pm[i], 16));
        pm[i] = fmaxf(pm[i], __shfl_xor(pm[i], 32));
        ps[i] += __shfl_xor(ps[i], 16);
        ps[i] += __shfl_xor(ps[i], 32);
    }
    __syncthreads();                           // x1t fully dead; red2 may overwrite
    if (rquad == 0) {
#pragma unroll
        for (int i = 0; i < 8; i++) {
            redM2[w * 128 + c0 + i] = pm[i];
            redS2[w * 128 + c0 + i] = ps[i];
        }
    }
    __syncthreads();
    if (tid < 128) {
        float M = -BINF, S = 0.f;
#pragma unroll
        for (int w2 = 0; w2 < 8; w2++) {
            M = fmaxf(M, redM2[w2 * 128 + tid]);
            S += redS2[w2 * 128 + tid];
        }
        partM2[(size_t)bx * 128 + tid] = M;
        partS2[(size_t)bx * 128 + tid] = S;
    }
}

// ---------------------------------------------------------------- final head
__global__ __launch_bounds__(256) void k_final(const float* __restrict__ partM1,
                                               const float* __restrict__ partS1,
                                               const float* __restrict__ partM2,
                                               const float* __restrict__ partS2,
                                               const float* __restrict__ fg_lw,
                                               const float* __restrict__ fg_lb,
                                               const float* __restrict__ fg_gw,
                                               const float* __restrict__ fg_gb,
                                               const float* __restrict__ out_w,
                                               const float* __restrict__ out_b,
                                               float* __restrict__ out) {
    __shared__ float pooled[512];
    __shared__ float linv[128], gatev[128];
    __shared__ float gluv[128];
    __shared__ float lg[2];
    int g = blockIdx.x, tid = threadIdx.x;

    const float* pM = (tid < 128) ? partM1 : partM2;
    const float* pS = (tid < 128) ? partS1 : partS2;
    int cc = tid & 127;
    float mx = -BINF, sm = 0.0f;
    for (int ch = 0; ch < 16; ch++) {
        mx = fmaxf(mx, pM[(size_t)(g * 16 + ch) * 128 + cc]);
        sm += pS[(size_t)(g * 16 + ch) * 128 + cc];
    }
    pooled[tid] = mx;
    pooled[256 + tid] = sm * (1.0f / 1024.0f);
    __syncthreads();

    float acc = 0.0f;
    if (tid < 128) {
        for (int k = 0; k < 512; k++) acc = fmaf(pooled[k], fg_lw[k * 128 + tid], acc);
        linv[tid] = acc + fg_lb[tid];
    } else {
        int c = tid - 128;
        for (int k = 0; k < 512; k++) acc = fmaf(pooled[k], fg_gw[k * 128 + c], acc);
        gatev[c] = acc + fg_gb[c];
    }
    __syncthreads();
    if (tid < 128) gluv[tid] = linv[tid] / (1.0f + expf(-gatev[tid]));
    __syncthreads();
    if (tid < 2) {
        float s = out_b[tid];
        for (int c = 0; c < 128; c++) s = fmaf(gluv[c], out_w[c * 2 + tid], s);
        lg[tid] = s;
    }
    __syncthreads();
    if (tid < 2) {
        float m = fmaxf(lg[0], lg[1]);
        float lse = m + logf(expf(lg[0] - m) + expf(lg[1] - m));
        out[g * 2 + tid] = lg[tid] - lse;
    }
}

// ---------------------------------------------------------------- launch
extern "C" void kernel_launch(void* const* d_in, const int* in_sizes, int n_in,
                              void* d_out, int out_size, void* d_ws, size_t ws_size,
                              hipStream_t stream) {
    const float* x     = (const float*)d_in[0];
    const float* te_w  = (const float*)d_in[1];
    const float* te_b  = (const float*)d_in[2];
    const float* ig_lw = (const float*)d_in[3];
    const float* ig_lb = (const float*)d_in[4];
    const float* ig_gw = (const float*)d_in[5];
    const float* ig_gb = (const float*)d_in[6];
    const float* c1_w  = (const float*)d_in[7];
    const float* c1_b  = (const float*)d_in[8];
    const float* c2_w  = (const float*)d_in[9];
    const float* c2_b  = (const float*)d_in[10];
    const float* fg_lw = (const float*)d_in[11];
    const float* fg_lb = (const float*)d_in[12];
    const float* fg_gw = (const float*)d_in[13];
    const float* fg_gb = (const float*)d_in[14];
    const float* out_w = (const float*)d_in[15];
    const float* out_b = (const float*)d_in[16];
    float* out = (float*)d_out;

    // workspace layout (~38 MB)
    char* p = (char*)d_ws;
    const size_t T16 = (size_t)NN * HID * sizeof(f16);   // 16 MB
    f16* A1 = (f16*)p; p += T16;
    f16* B1 = (f16*)p; p += T16;
    int* sidxg = (int*)p;            p += (size_t)NN * 4;
    short* nbroff = (short*)p;       p += (size_t)NN * KNN * 2;
    float* partM1 = (float*)p;       p += (size_t)1024 * 128 * 4;
    float* partS1 = (float*)p;       p += (size_t)1024 * 128 * 4;
    float* partM2 = (float*)p;       p += (size_t)1024 * 128 * 4;
    float* partS2 = (float*)p;       p += (size_t)1024 * 128 * 4;
    f16* gfrag = (f16*)p;            p += 16384 * 2;
    f16* f1 = (f16*)p;               p += 32768 * 2;
    f16* f2 = (f16*)p;               p += 32768 * 2;

    k_topk<<<NG + 80, 1024, 0, stream>>>(x, sidxg, nbroff, ig_lw, ig_gw,
                                         c1_w, c2_w, gfrag, f1, f2);
    k_fuse1<<<NN / 64, 256, 0, stream>>>(x, te_w, te_b, (const f16x8*)gfrag,
                                         ig_lb, ig_gb, sidxg, (const f16x8*)f1,
                                         c1_b, A1, B1);
    k_megac2<<<NN / 64, 512, 0, stream>>>(A1, B1, nbroff, (const f16x8*)f2,
                                          c2_b, partM1, partS1, partM2, partS2);
    k_final<<<NG, 256, 0, stream>>>(partM1, partS1, partM2, partS2,
                                    fg_lw, fg_lb, fg_gw, fg_gb, out_w, out_b, out);
}

// Round 15
// 103.377 us; speedup vs baseline: 1.0068x; 1.0068x over previous
//
#include <hip/hip_runtime.h>
#include <math.h>

#define NN 65536
#define NG 64
#define NPG 1024
#define HID 128
#define KNN 16
#define BINF 1e30f
#define BWS 272            // padded LDS row stride (bytes): 17*16B -> dRow=4 => dBank=16

typedef unsigned long long ull;
typedef _Float16 f16;
typedef _Float16 f16x8 __attribute__((ext_vector_type(8)));
typedef float f32x4 __attribute__((ext_vector_type(4)));

// ---------------------------------------------------------------- kNN sort + weight prep
__global__ __launch_bounds__(1024) void k_topk(
    const float* __restrict__ x, int* __restrict__ sidxg,
    short* __restrict__ nbroff,
    const float* __restrict__ ig_lw, const float* __restrict__ ig_gw,
    const float* __restrict__ c1_w, const float* __restrict__ c2_w,
    f16* __restrict__ gfrag, f16* __restrict__ f1, f16* __restrict__ f2) {
    __shared__ ull key[1024];
    __shared__ float st[1024];
    __shared__ int sidx[1024];
    int g = blockIdx.x;
    if (g >= NG) {
        int gid = (g - NG) * 1024 + threadIdx.x;   // [0, 81920)
        if (gid < 16384) {
            int i = gid & 7, lane = (gid >> 3) & 63, nt = (gid >> 9) & 7;
            int kt = (gid >> 12) & 1, mat = gid >> 13;
            int k = kt * 32 + ((lane >> 4) << 3) + i;
            int c = nt * 16 + (lane & 15);
            float v = 0.0f;
            if (k < 48) v = (mat ? ig_gw : ig_lw)[k * 128 + c];
            gfrag[gid] = (f16)v;
        } else {
            int g2 = gid - 16384;
            int buf = g2 >> 15;
            int rem = g2 & 32767;
            int mat = rem >> 14;
            int r2 = rem & 16383;
            int i = r2 & 7, lane = (r2 >> 3) & 63, nt = (r2 >> 9) & 7, kt = (r2 >> 12) & 3;
            int k = kt * 32 + ((lane >> 4) << 3) + i;
            int c = nt * 16 + (lane & 15);
            const float* cw = buf ? c2_w : c1_w;
            float top = cw[k * 128 + c];
            float bot = cw[(128 + k) * 128 + c];
            float v = mat ? bot : (top - bot);
            (buf ? f2 : f1)[rem] = (f16)v;
        }
        return;
    }
    int i = threadIdx.x;
    float t = x[(size_t)(g * NPG + i) * 17];
    unsigned ub = __float_as_uint(t);
    ub = (ub & 0x80000000u) ? ~ub : (ub | 0x80000000u);   // order-preserving map
    ull kk = ((ull)ub << 32) | (unsigned)i;

    for (int k = 2; k <= 1024; k <<= 1) {
        for (int j = k >> 1; j > 0; j >>= 1) {
            ull pv;
            if (j >= 64) {
                key[i] = kk;
                __syncthreads();
                pv = key[i ^ j];
                __syncthreads();
            } else {
                pv = __shfl_xor(kk, j, 64);
            }
            bool up = ((i & k) == 0);
            bool low = ((i & j) == 0);
            ull mn = kk < pv ? kk : pv;
            ull mx = kk < pv ? pv : kk;
            kk = (up == low) ? mn : mx;
        }
    }
    int oi = (int)(kk & 0xffffffffu);
    st[i] = x[(size_t)(g * NPG + oi) * 17];
    sidx[i] = oi;
    sidxg[g * NPG + i] = g * NPG + oi;
    __syncthreads();

    // two-pointer merge in rank space; offsets pre-scaled by LDS row stride
    float tt = st[i];
    int L = i - 1, R = i + 1;
    short* out = nbroff + (size_t)(g * NPG + i) * KNN;
#pragma unroll
    for (int q = 0; q < KNN; q++) {
        float dl = (L >= 0)   ? (tt - st[L]) : BINF;
        float dr = (R < NPG) ? (st[R] - tt) : BINF;
        bool left;
        if (dl < dr) left = true;
        else if (dr < dl) left = false;
        else left = (sidx[L] < sidx[R]);   // tie: lower original index (lax.top_k)
        int jr;
        if (left) { jr = L; L--; }
        else      { jr = R; R++; }
        out[q] = (short)((jr - i) * BWS);
    }
}

// ---------------------------------------------------------------- fused GLU + conv1
__global__ __launch_bounds__(256) void k_fuse1(
    const float* __restrict__ x, const float* __restrict__ te_w,
    const float* __restrict__ te_b, const f16x8* __restrict__ gfrag,
    const float* __restrict__ bl, const float* __restrict__ bg,
    const int* __restrict__ sidxg, const f16x8* __restrict__ wfrag,
    const float* __restrict__ cb, f16* __restrict__ A, f16* __restrict__ B) {
    __shared__ f16x8 XL[4 * 2 * 64];          // Z fragments [mf][kt][lane]
    __shared__ f16 ht[64 * 128];              // XOR-swizzled H tile
    int tid = threadIdx.x;
    int r0 = blockIdx.x * 64;
#pragma unroll
    for (int p = 0; p < 2; p++) {
        int idx = tid + p * 256;              // [0,512)
        int row = idx >> 3, kq = idx & 7;
        int node = sidxg[r0 + row];
        f16x8 h;
        if (kq < 2) {
            const float* xr = x + (size_t)node * 17 + 1 + kq * 8;
#pragma unroll
            for (int i = 0; i < 8; i++) h[i] = (f16)xr[i];
        } else if (kq < 6) {
            float t = x[(size_t)node * 17];
            int j0 = (kq - 2) * 8;
#pragma unroll
            for (int i = 0; i < 8; i++) h[i] = (f16)fmaf(t, te_w[j0 + i], te_b[j0 + i]);
        } else {
#pragma unroll
            for (int i = 0; i < 8; i++) h[i] = (f16)0.0f;
        }
        int mf = row >> 4, kt = kq >> 2, lane = ((kq & 3) << 4) | (row & 15);
        XL[(mf * 2 + kt) * 64 + lane] = h;
    }
    __syncthreads();
    int w = tid >> 6, lane = tid & 63;
    f32x4 acc[2][2][4];
#pragma unroll
    for (int o = 0; o < 2; o++)
#pragma unroll
        for (int j = 0; j < 2; j++)
#pragma unroll
            for (int mf = 0; mf < 4; mf++) acc[o][j][mf] = (f32x4){0.f, 0.f, 0.f, 0.f};
    __builtin_amdgcn_s_setprio(1);
#pragma unroll 1
    for (int kt = 0; kt < 2; kt++) {
        f16x8 wf0[2], wf1[2], xa[4];
#pragma unroll
        for (int j = 0; j < 2; j++) {
            wf0[j] = gfrag[((0 * 2 + kt) * 8 + (w * 2 + j)) * 64 + lane];
            wf1[j] = gfrag[((1 * 2 + kt) * 8 + (w * 2 + j)) * 64 + lane];
        }
#pragma unroll
        for (int mf = 0; mf < 4; mf++) xa[mf] = XL[(mf * 2 + kt) * 64 + lane];
#pragma unroll
        for (int mf = 0; mf < 4; mf++)
#pragma unroll
            for (int j = 0; j < 2; j++) {
                acc[0][j][mf] = __builtin_amdgcn_mfma_f32_16x16x32_f16(xa[mf], wf0[j], acc[0][j][mf], 0, 0, 0);
                acc[1][j][mf] = __builtin_amdgcn_mfma_f32_16x16x32_f16(xa[mf], wf1[j], acc[1][j][mf], 0, 0, 0);
            }
    }
    __builtin_amdgcn_s_setprio(0);
    // GLU epilogue -> swizzled LDS tile
#pragma unroll
    for (int j = 0; j < 2; j++) {
        int col = w * 32 + j * 16 + (lane & 15);
        float bbl = bl[col], bbg = bg[col];
#pragma unroll
        for (int mf = 0; mf < 4; mf++) {
            int rloc = mf * 16 + ((lane >> 4) << 2);
#pragma unroll
            for (int q = 0; q < 4; q++) {
                float lin = acc[0][j][mf][q] + bbl;
                float gat = acc[1][j][mf][q] + bbg;
                int row = rloc + q;
                ht[(row * 128 + col) ^ ((row & 7) << 3)] = (f16)(lin / (1.0f + expf(-gat)));
            }
        }
    }
    __syncthreads();
    // conv1 dual GEMM from ht
#pragma unroll
    for (int o = 0; o < 2; o++)
#pragma unroll
        for (int j = 0; j < 2; j++)
#pragma unroll
            for (int mf = 0; mf < 4; mf++) acc[o][j][mf] = (f32x4){0.f, 0.f, 0.f, 0.f};
    int row16 = lane & 15, kslot = lane >> 4;
    int swz = (row16 & 7) << 3;
    __builtin_amdgcn_s_setprio(1);
#pragma unroll 1
    for (int kt = 0; kt < 4; kt++) {
        f16x8 wf0[2], wf1[2], xa[4];
#pragma unroll
        for (int j = 0; j < 2; j++) {
            wf0[j] = wfrag[((0 * 4 + kt) * 8 + (w * 2 + j)) * 64 + lane];
            wf1[j] = wfrag[((1 * 4 + kt) * 8 + (w * 2 + j)) * 64 + lane];
        }
#pragma unroll
        for (int mf = 0; mf < 4; mf++)
            xa[mf] = *(const f16x8*)&ht[((mf * 16 + row16) * 128 + kt * 32 + kslot * 8) ^ swz];
#pragma unroll
        for (int mf = 0; mf < 4; mf++)
#pragma unroll
            for (int j = 0; j < 2; j++) {
                acc[0][j][mf] = __builtin_amdgcn_mfma_f32_16x16x32_f16(xa[mf], wf0[j], acc[0][j][mf], 0, 0, 0);
                acc[1][j][mf] = __builtin_amdgcn_mfma_f32_16x16x32_f16(xa[mf], wf1[j], acc[1][j][mf], 0, 0, 0);
            }
    }
    __builtin_amdgcn_s_setprio(0);
#pragma unroll
    for (int j = 0; j < 2; j++) {
        int col = w * 32 + j * 16 + (lane & 15);
        float bias = cb[col];
#pragma unroll
        for (int mf = 0; mf < 4; mf++) {
            int rbase = r0 + mf * 16 + ((lane >> 4) << 2);
#pragma unroll
            for (int q = 0; q < 4; q++) {
                A[(size_t)(rbase + q) * 128 + col] = (f16)(acc[0][j][mf][q] + bias);
                B[(size_t)(rbase + q) * 128 + col] = (f16)acc[1][j][mf][q];
            }
        }
    }
}

// ---------------------------------------------------------------- conv2 + gather2 + pools
// 512 threads / 8 waves; LDS 79.9KB -> 2 blocks/CU = 16 waves/CU.
// Neighbor offsets staged in LDS (nbrL): gather critical path has no global dep.
__global__ __launch_bounds__(512) void k_megac2(
    const f16* __restrict__ A1, const f16* __restrict__ B1,
    const short* __restrict__ nbroff, const f16x8* __restrict__ wfrag,
    const float* __restrict__ cb,
    float* __restrict__ partM1, float* __restrict__ partS1,
    float* __restrict__ partM2, float* __restrict__ partS2) {
    __shared__ char SM[79872];
    char* bw  = SM;                            // B1 window: 128 rows x BWS
    char* b2  = SM;                            // B2: 96 rows x BWS (aliases bw post-gather1)
    f16*  x1t = (f16*)(SM + 34816);            // 96x128 f16 swizzled (24576 B)
    char* a2  = SM + 59392;                    // A2: 64 rows x BWS (17408 B)
    float* redM1 = (float*)(SM + 59392);       // 8x128 f32, aliases a2 (pre-epilogue)
    float* redS1 = (float*)(SM + 63488);
    float* redM2 = (float*)(SM + 34816);       // 8x128 f32, aliases x1t (post-GEMM)
    float* redS2 = (float*)(SM + 38912);
    short* nbrL = (short*)(SM + 76800);        // 96 rows x 16 shorts (3072 B)

    int tid = threadIdx.x;
    int bx = blockIdx.x;
    int r0 = bx * 64;
    int r0loc = (bx & 15) * 64;
    int gbase = r0 - r0loc;                    // graph base row

    // ---- stage B1 window ranks [r0loc-32, r0loc+96): 2048 octets, 4 passes
#pragma unroll
    for (int p = 0; p < 4; p++) {
        int idx = tid + p * 512;               // [0,2048)
        int row = idx >> 4, kq = idx & 15;
        int gl = r0loc - 32 + row;
        f16x8 v;
#pragma unroll
        for (int i = 0; i < 8; i++) v[i] = (f16)0.0f;
        if (gl >= 0 && gl < NPG)
            v = *(const f16x8*)(B1 + (size_t)(gbase + gl) * 128 + kq * 8);
        *(f16x8*)(bw + row * BWS + kq * 16) = v;
    }
    // ---- stage neighbor offsets for ranks [r0loc-16, r0loc+80)
    if (tid < 192) {
        int row = tid >> 1, half = tid & 1;
        int gl = r0loc - 16 + row;
        int4 v = {0, 0, 0, 0};
        if (gl >= 0 && gl < NPG)
            v = ((const int4*)(nbroff + (size_t)(gbase + gl) * KNN))[half];
        ((int4*)nbrL)[tid] = v;
    }
    __syncthreads();

    int w = tid >> 6, lane = tid & 63;         // w in [0,8)
    int rquad = lane >> 4;
    int c0 = (lane & 15) * 8;

    // ---- gather1: x1 for 96 halo rows (12 rows/wave); pool interior [16,80)
    f16x8 pmv;
    float ps[8];
#pragma unroll
    for (int i = 0; i < 8; i++) { pmv[i] = (f16)(-INFINITY); ps[i] = 0.f; }
    // preload offset vectors for this thread's 3 rows (LDS, issue-independent)
    short ow0[16], ow1[16], ow2[16];
    {
        int row0 = w * 12 + 0 * 4 + rquad;
        int row1 = w * 12 + 1 * 4 + rquad;
        int row2 = w * 12 + 2 * 4 + rquad;
        *(int4*)&ow0[0] = ((const int4*)nbrL)[row0 * 2];
        *(int4*)&ow0[8] = ((const int4*)nbrL)[row0 * 2 + 1];
        *(int4*)&ow1[0] = ((const int4*)nbrL)[row1 * 2];
        *(int4*)&ow1[8] = ((const int4*)nbrL)[row1 * 2 + 1];
        *(int4*)&ow2[0] = ((const int4*)nbrL)[row2 * 2];
        *(int4*)&ow2[8] = ((const int4*)nbrL)[row2 * 2 + 1];
    }
#pragma unroll
    for (int rr = 0; rr < 3; rr++) {
        const short* ow = (rr == 0) ? ow0 : (rr == 1) ? ow1 : ow2;
        int row = w * 12 + rr * 4 + rquad;     // [0,96)
        int gl = r0loc - 16 + row;
        f16x8 ou;
#pragma unroll
        for (int i = 0; i < 8; i++) ou[i] = (f16)0.0f;
        if (gl >= 0 && gl < NPG) {
            int grow = gbase + gl;
            f16x8 av = *(const f16x8*)(A1 + (size_t)grow * 128 + c0);
            f16x8 m;
#pragma unroll
            for (int i = 0; i < 8; i++) m[i] = (f16)(-INFINITY);
            const char* base = bw + (row + 16) * BWS + c0 * 2;
#pragma unroll
            for (int q = 0; q < 16; q++) {
                f16x8 bv = *(const f16x8*)(base + (int)ow[q]);
                m = __builtin_elementwise_max(m, bv);
            }
            f16x8 z = {(f16)0, (f16)0, (f16)0, (f16)0, (f16)0, (f16)0, (f16)0, (f16)0};
            ou = __builtin_elementwise_max(av + m, z);
            if ((row >= 16) && (row < 80)) {
                pmv = __builtin_elementwise_max(pmv, ou);
#pragma unroll
                for (int i = 0; i < 8; i++) ps[i] += (float)ou[i];
            }
        }
        int idx = (row * 128 + c0) ^ ((row & 7) << 3);
        *(f16x8*)&x1t[idx] = ou;
    }
    // x1 pool reduce (red1 aliases a2 region; a2 not yet written)
    float pm[8];
#pragma unroll
    for (int i = 0; i < 8; i++) pm[i] = (float)pmv[i];
#pragma unroll
    for (int i = 0; i < 8; i++) {
        pm[i] = fmaxf(pm[i], __shfl_xor(pm[i], 16));
        pm[i] = fmaxf(pm[i], __shfl_xor(pm[i], 32));
        ps[i] += __shfl_xor(ps[i], 16);
        ps[i] += __shfl_xor(ps[i], 32);
    }
    if (rquad == 0) {
#pragma unroll
        for (int i = 0; i < 8; i++) {
            redM1[w * 128 + c0 + i] = pm[i];
            redS1[w * 128 + c0 + i] = ps[i];
        }
    }
    __syncthreads();
    if (tid < 128) {
        float M = -BINF, S = 0.f;
#pragma unroll
        for (int w2 = 0; w2 < 8; w2++) {
            M = fmaxf(M, redM1[w2 * 128 + tid]);
            S += redS1[w2 * 128 + tid];
        }
        partM1[(size_t)bx * 128 + tid] = M;
        partS1[(size_t)bx * 128 + tid] = S;
    }
    __syncthreads();                           // red1 consumed before a2 epilogue writes

    // ---- dual GEMM over 96 rows: each wave one 16-col N-frag
    f32x4 acc[2][6];                           // [out][mf]
#pragma unroll
    for (int o = 0; o < 2; o++)
#pragma unroll
        for (int mf = 0; mf < 6; mf++) acc[o][mf] = (f32x4){0.f, 0.f, 0.f, 0.f};
    int row16 = lane & 15, kslot = lane >> 4;
    int swz = (row16 & 7) << 3;
    __builtin_amdgcn_s_setprio(1);
#pragma unroll 1
    for (int kt = 0; kt < 4; kt++) {
        f16x8 wf0, wf1, xa[6];
        wf0 = wfrag[((0 * 4 + kt) * 8 + w) * 64 + lane];
        wf1 = wfrag[((1 * 4 + kt) * 8 + w) * 64 + lane];
#pragma unroll
        for (int mf = 0; mf < 6; mf++)
            xa[mf] = *(const f16x8*)&x1t[((mf * 16 + row16) * 128 + kt * 32 + kslot * 8) ^ swz];
#pragma unroll
        for (int mf = 0; mf < 6; mf++) {
            acc[0][mf] = __builtin_amdgcn_mfma_f32_16x16x32_f16(xa[mf], wf0, acc[0][mf], 0, 0, 0);
            acc[1][mf] = __builtin_amdgcn_mfma_f32_16x16x32_f16(xa[mf], wf1, acc[1][mf], 0, 0, 0);
        }
    }
    __builtin_amdgcn_s_setprio(0);
    // epilogue -> LDS (B2 all 96 rows; A2 interior 64 rows)
    {
        int col = w * 16 + (lane & 15);
        float bias = cb[col];
#pragma unroll
        for (int mf = 0; mf < 6; mf++) {
            int rloc = mf * 16 + ((lane >> 4) << 2);
#pragma unroll
            for (int q = 0; q < 4; q++) {
                int hrow = rloc + q;           // [0,96)
                *(f16*)(b2 + hrow * BWS + col * 2) = (f16)acc[1][mf][q];
                if (hrow >= 16 && hrow < 80)
                    *(f16*)(a2 + (hrow - 16) * BWS + col * 2) = (f16)(acc[0][mf][q] + bias);
            }
        }
    }
    __syncthreads();                           // GEMM x1t reads done; a2/b2 visible

    // ---- gather2 + pool (interior 64 rows, 8 rows/wave), all from LDS
#pragma unroll
    for (int i = 0; i < 8; i++) { pmv[i] = (f16)(-INFINITY); ps[i] = 0.f; }
    short og0[16], og1[16];
    {
        int rl0 = w * 8 + 0 * 4 + rquad;
        int rl1 = w * 8 + 1 * 4 + rquad;
        *(int4*)&og0[0] = ((const int4*)nbrL)[(rl0 + 16) * 2];
        *(int4*)&og0[8] = ((const int4*)nbrL)[(rl0 + 16) * 2 + 1];
        *(int4*)&og1[0] = ((const int4*)nbrL)[(rl1 + 16) * 2];
        *(int4*)&og1[8] = ((const int4*)nbrL)[(rl1 + 16) * 2 + 1];
    }
#pragma unroll
    for (int rr = 0; rr < 2; rr++) {
        const short* ow = (rr == 0) ? og0 : og1;
        int rl = w * 8 + rr * 4 + rquad;       // [0,64)
        f16x8 av = *(const f16x8*)(a2 + rl * BWS + c0 * 2);
        f16x8 m;
#pragma unroll
        for (int i = 0; i < 8; i++) m[i] = (f16)(-INFINITY);
        const char* base = b2 + (rl + 16) * BWS + c0 * 2;
#pragma unroll
        for (int q = 0; q < 16; q++) {
            f16x8 bv = *(const f16x8*)(base + (int)ow[q]);
            m = __builtin_elementwise_max(m, bv);
        }
        f16x8 z = {(f16)0, (f16)0, (f16)0, (f16)0, (f16)0, (f16)0, (f16)0, (f16)0};
        f16x8 v = __builtin_elementwise_max(av + m, z);
        pmv = __builtin_elementwise_max(pmv, v);
#pragma unroll
        for (int i = 0; i < 8; i++) ps[i] += (float)v[i];
    }
#pragma unroll
    for (int i = 0; i < 8; i++) pm[i] = (float)pmv[i];
#pragma unroll
    for (int i = 0; i < 8; i++) {
        pm[i] = fmaxf(pm[i], __shfl_xor(pm[i], 16));
        pm[i] = fmaxf(pm[i], __shfl_xor(pm[i], 32));
        ps[i] += __shfl_xor(ps[i], 16);
        ps[i] += __shfl_xor(ps[i], 32);
    }
    __syncthreads();                           // x1t fully dead; red2 may overwrite
    if (rquad == 0) {
#pragma unroll
        for (int i = 0; i < 8; i++) {
            redM2[w * 128 + c0 + i] = pm[i];
            redS2[w * 128 + c0 + i] = ps[i];
        }
    }
    __syncthreads();
    if (tid < 128) {
        float M = -BINF, S = 0.f;
#pragma unroll
        for (int w2 = 0; w2 < 8; w2++) {
            M = fmaxf(M, redM2[w2 * 128 + tid]);
            S += redS2[w2 * 128 + tid];
        }
        partM2[(size_t)bx * 128 + tid] = M;
        partS2[(size_t)bx * 128 + tid] = S;
    }
}

// ---------------------------------------------------------------- final head
__global__ __launch_bounds__(256) void k_final(const float* __restrict__ partM1,
                                               const float* __restrict__ partS1,
                                               const float* __restrict__ partM2,
                                               const float* __restrict__ partS2,
                                               const float* __restrict__ fg_lw,
                                               const float* __restrict__ fg_lb,
                                               const float* __restrict__ fg_gw,
                                               const float* __restrict__ fg_gb,
                                               const float* __restrict__ out_w,
                                               const float* __restrict__ out_b,
                                               float* __restrict__ out) {
    __shared__ float pooled[512];
    __shared__ float linv[128], gatev[128];
    __shared__ float gluv[128];
    __shared__ float lg[2];
    int g = blockIdx.x, tid = threadIdx.x;

    const float* pM = (tid < 128) ? partM1 : partM2;
    const float* pS = (tid < 128) ? partS1 : partS2;
    int cc = tid & 127;
    float mx = -BINF, sm = 0.0f;
    for (int ch = 0; ch < 16; ch++) {
        mx = fmaxf(mx, pM[(size_t)(g * 16 + ch) * 128 + cc]);
        sm += pS[(size_t)(g * 16 + ch) * 128 + cc];
    }
    pooled[tid] = mx;
    pooled[256 + tid] = sm * (1.0f / 1024.0f);
    __syncthreads();

    float acc = 0.0f;
    if (tid < 128) {
        for (int k = 0; k < 512; k++) acc = fmaf(pooled[k], fg_lw[k * 128 + tid], acc);
        linv[tid] = acc + fg_lb[tid];
    } else {
        int c = tid - 128;
        for (int k = 0; k < 512; k++) acc = fmaf(pooled[k], fg_gw[k * 128 + c], acc);
        gatev[c] = acc + fg_gb[c];
    }
    __syncthreads();
    if (tid < 128) gluv[tid] = linv[tid] / (1.0f + expf(-gatev[tid]));
    __syncthreads();
    if (tid < 2) {
        float s = out_b[tid];
        for (int c = 0; c < 128; c++) s = fmaf(gluv[c], out_w[c * 2 + tid], s);
        lg[tid] = s;
    }
    __syncthreads();
    if (tid < 2) {
        float m = fmaxf(lg[0], lg[1]);
        float lse = m + logf(expf(lg[0] - m) + expf(lg[1] - m));
        out[g * 2 + tid] = lg[tid] - lse;
    }
}

// ---------------------------------------------------------------- launch
extern "C" void kernel_launch(void* const* d_in, const int* in_sizes, int n_in,
                              void* d_out, int out_size, void* d_ws, size_t ws_size,
                              hipStream_t stream) {
    const float* x     = (const float*)d_in[0];
    const float* te_w  = (const float*)d_in[1];
    const float* te_b  = (const float*)d_in[2];
    const float* ig_lw = (const float*)d_in[3];
    const float* ig_lb = (const float*)d_in[4];
    const float* ig_gw = (const float*)d_in[5];
    const float* ig_gb = (const float*)d_in[6];
    const float* c1_w  = (const float*)d_in[7];
    const float* c1_b  = (const float*)d_in[8];
    const float* c2_w  = (const float*)d_in[9];
    const float* c2_b  = (const float*)d_in[10];
    const float* fg_lw = (const float*)d_in[11];
    const float* fg_lb = (const float*)d_in[12];
    const float* fg_gw = (const float*)d_in[13];
    const float* fg_gb = (const float*)d_in[14];
    const float* out_w = (const float*)d_in[15];
    const float* out_b = (const float*)d_in[16];
    float* out = (float*)d_out;

    // workspace layout (~38 MB)
    char* p = (char*)d_ws;
    const size_t T16 = (size_t)NN * HID * sizeof(f16);   // 16 MB
    f16* A1 = (f16*)p; p += T16;
    f16* B1 = (f16*)p; p += T16;
    int* sidxg = (int*)p;            p += (size_t)NN * 4;
    short* nbroff = (short*)p;       p += (size_t)NN * KNN * 2;
    float* partM1 = (float*)p;       p += (size_t)1024 * 128 * 4;
    float* partS1 = (float*)p;       p += (size_t)1024 * 128 * 4;
    float* partM2 = (float*)p;       p += (size_t)1024 * 128 * 4;
    float* partS2 = (float*)p;       p += (size_t)1024 * 128 * 4;
    f16* gfrag = (f16*)p;            p += 16384 * 2;
    f16* f1 = (f16*)p;               p += 32768 * 2;
    f16* f2 = (f16*)p;               p += 32768 * 2;

    k_topk<<<NG + 80, 1024, 0, stream>>>(x, sidxg, nbroff, ig_lw, ig_gw,
                                         c1_w, c2_w, gfrag, f1, f2);
    k_fuse1<<<NN / 64, 256, 0, stream>>>(x, te_w, te_b, (const f16x8*)gfrag,
                                         ig_lb, ig_gb, sidxg, (const f16x8*)f1,
                                         c1_b, A1, B1);
    k_megac2<<<NN / 64, 512, 0, stream>>>(A1, B1, nbroff, (const f16x8*)f2,
                                          c2_b, partM1, partS1, partM2, partS2);
    k_final<<<NG, 256, 0, stream>>>(partM1, partS1, partM2, partS2,
                                    fg_lw, fg_lb, fg_gw, fg_gb, out_w, out_b, out);
}

// Round 16
// 102.469 us; speedup vs baseline: 1.0157x; 1.0089x over previous
//
#include <hip/hip_runtime.h>
#include <math.h>

#define NN 65536
#define NG 64
#define NPG 1024
#define HID 128
#define KNN 16
#define BINF 1e30f
#define BWS 272            // padded LDS row stride (bytes): 17*16B -> dRow=4 => dBank=16

typedef unsigned long long ull;
typedef _Float16 f16;
typedef _Float16 f16x8 __attribute__((ext_vector_type(8)));
typedef float f32x4 __attribute__((ext_vector_type(4)));

// ---------------------------------------------------------------- kNN sort + weight prep
__global__ __launch_bounds__(1024) void k_topk(
    const float* __restrict__ x, int* __restrict__ sidxg,
    short* __restrict__ nbroff,
    const float* __restrict__ ig_lw, const float* __restrict__ ig_gw,
    const float* __restrict__ c1_w, const float* __restrict__ c2_w,
    f16* __restrict__ gfrag, f16* __restrict__ f1, f16* __restrict__ f2) {
    __shared__ ull key[1024];
    __shared__ float st[1024];
    __shared__ int sidx[1024];
    int g = blockIdx.x;
    if (g >= NG) {
        int gid = (g - NG) * 1024 + threadIdx.x;   // [0, 81920)
        if (gid < 16384) {
            int i = gid & 7, lane = (gid >> 3) & 63, nt = (gid >> 9) & 7;
            int kt = (gid >> 12) & 1, mat = gid >> 13;
            int k = kt * 32 + ((lane >> 4) << 3) + i;
            int c = nt * 16 + (lane & 15);
            float v = 0.0f;
            if (k < 48) v = (mat ? ig_gw : ig_lw)[k * 128 + c];
            gfrag[gid] = (f16)v;
        } else {
            int g2 = gid - 16384;
            int buf = g2 >> 15;
            int rem = g2 & 32767;
            int mat = rem >> 14;
            int r2 = rem & 16383;
            int i = r2 & 7, lane = (r2 >> 3) & 63, nt = (r2 >> 9) & 7, kt = (r2 >> 12) & 3;
            int k = kt * 32 + ((lane >> 4) << 3) + i;
            int c = nt * 16 + (lane & 15);
            const float* cw = buf ? c2_w : c1_w;
            float top = cw[k * 128 + c];
            float bot = cw[(128 + k) * 128 + c];
            float v = mat ? bot : (top - bot);
            (buf ? f2 : f1)[rem] = (f16)v;
        }
        return;
    }
    int i = threadIdx.x;
    float t = x[(size_t)(g * NPG + i) * 17];
    unsigned ub = __float_as_uint(t);
    ub = (ub & 0x80000000u) ? ~ub : (ub | 0x80000000u);   // order-preserving map
    ull kk = ((ull)ub << 32) | (unsigned)i;

    for (int k = 2; k <= 1024; k <<= 1) {
        for (int j = k >> 1; j > 0; j >>= 1) {
            ull pv;
            if (j >= 64) {
                key[i] = kk;
                __syncthreads();
                pv = key[i ^ j];
                __syncthreads();
            } else {
                pv = __shfl_xor(kk, j, 64);
            }
            bool up = ((i & k) == 0);
            bool low = ((i & j) == 0);
            ull mn = kk < pv ? kk : pv;
            ull mx = kk < pv ? pv : kk;
            kk = (up == low) ? mn : mx;
        }
    }
    int oi = (int)(kk & 0xffffffffu);
    st[i] = x[(size_t)(g * NPG + oi) * 17];
    sidx[i] = oi;
    sidxg[g * NPG + i] = g * NPG + oi;
    __syncthreads();

    // two-pointer merge in rank space; offsets pre-scaled by LDS row stride
    float tt = st[i];
    int L = i - 1, R = i + 1;
    short* out = nbroff + (size_t)(g * NPG + i) * KNN;
#pragma unroll
    for (int q = 0; q < KNN; q++) {
        float dl = (L >= 0)   ? (tt - st[L]) : BINF;
        float dr = (R < NPG) ? (st[R] - tt) : BINF;
        bool left;
        if (dl < dr) left = true;
        else if (dr < dl) left = false;
        else left = (sidx[L] < sidx[R]);   // tie: lower original index (lax.top_k)
        int jr;
        if (left) { jr = L; L--; }
        else      { jr = R; R++; }
        out[q] = (short)((jr - i) * BWS);
    }
}

// ---------------------------------------------------------------- fused GLU + conv1
__global__ __launch_bounds__(256) void k_fuse1(
    const float* __restrict__ x, const float* __restrict__ te_w,
    const float* __restrict__ te_b, const f16x8* __restrict__ gfrag,
    const float* __restrict__ bl, const float* __restrict__ bg,
    const int* __restrict__ sidxg, const f16x8* __restrict__ wfrag,
    const float* __restrict__ cb, f16* __restrict__ A, f16* __restrict__ B) {
    __shared__ f16x8 XL[4 * 2 * 64];          // Z fragments [mf][kt][lane]
    __shared__ f16 ht[64 * 128];              // XOR-swizzled H tile
    int tid = threadIdx.x;
    int r0 = blockIdx.x * 64;
#pragma unroll
    for (int p = 0; p < 2; p++) {
        int idx = tid + p * 256;              // [0,512)
        int row = idx >> 3, kq = idx & 7;
        int node = sidxg[r0 + row];
        f16x8 h;
        if (kq < 2) {
            const float* xr = x + (size_t)node * 17 + 1 + kq * 8;
#pragma unroll
            for (int i = 0; i < 8; i++) h[i] = (f16)xr[i];
        } else if (kq < 6) {
            float t = x[(size_t)node * 17];
            int j0 = (kq - 2) * 8;
#pragma unroll
            for (int i = 0; i < 8; i++) h[i] = (f16)fmaf(t, te_w[j0 + i], te_b[j0 + i]);
        } else {
#pragma unroll
            for (int i = 0; i < 8; i++) h[i] = (f16)0.0f;
        }
        int mf = row >> 4, kt = kq >> 2, lane = ((kq & 3) << 4) | (row & 15);
        XL[(mf * 2 + kt) * 64 + lane] = h;
    }
    __syncthreads();
    int w = tid >> 6, lane = tid & 63;
    f32x4 acc[2][2][4];
#pragma unroll
    for (int o = 0; o < 2; o++)
#pragma unroll
        for (int j = 0; j < 2; j++)
#pragma unroll
            for (int mf = 0; mf < 4; mf++) acc[o][j][mf] = (f32x4){0.f, 0.f, 0.f, 0.f};
#pragma unroll 1
    for (int kt = 0; kt < 2; kt++) {
        f16x8 wf0[2], wf1[2], xa[4];
#pragma unroll
        for (int j = 0; j < 2; j++) {
            wf0[j] = gfrag[((0 * 2 + kt) * 8 + (w * 2 + j)) * 64 + lane];
            wf1[j] = gfrag[((1 * 2 + kt) * 8 + (w * 2 + j)) * 64 + lane];
        }
#pragma unroll
        for (int mf = 0; mf < 4; mf++) xa[mf] = XL[(mf * 2 + kt) * 64 + lane];
#pragma unroll
        for (int mf = 0; mf < 4; mf++)
#pragma unroll
            for (int j = 0; j < 2; j++) {
                acc[0][j][mf] = __builtin_amdgcn_mfma_f32_16x16x32_f16(xa[mf], wf0[j], acc[0][j][mf], 0, 0, 0);
                acc[1][j][mf] = __builtin_amdgcn_mfma_f32_16x16x32_f16(xa[mf], wf1[j], acc[1][j][mf], 0, 0, 0);
            }
    }
    // GLU epilogue -> swizzled LDS tile
#pragma unroll
    for (int j = 0; j < 2; j++) {
        int col = w * 32 + j * 16 + (lane & 15);
        float bbl = bl[col], bbg = bg[col];
#pragma unroll
        for (int mf = 0; mf < 4; mf++) {
            int rloc = mf * 16 + ((lane >> 4) << 2);
#pragma unroll
            for (int q = 0; q < 4; q++) {
                float lin = acc[0][j][mf][q] + bbl;
                float gat = acc[1][j][mf][q] + bbg;
                int row = rloc + q;
                ht[(row * 128 + col) ^ ((row & 7) << 3)] = (f16)(lin / (1.0f + expf(-gat)));
            }
        }
    }
    __syncthreads();
    // conv1 dual GEMM from ht
#pragma unroll
    for (int o = 0; o < 2; o++)
#pragma unroll
        for (int j = 0; j < 2; j++)
#pragma unroll
            for (int mf = 0; mf < 4; mf++) acc[o][j][mf] = (f32x4){0.f, 0.f, 0.f, 0.f};
    int row16 = lane & 15, kslot = lane >> 4;
    int swz = (row16 & 7) << 3;
#pragma unroll 1
    for (int kt = 0; kt < 4; kt++) {
        f16x8 wf0[2], wf1[2], xa[4];
#pragma unroll
        for (int j = 0; j < 2; j++) {
            wf0[j] = wfrag[((0 * 4 + kt) * 8 + (w * 2 + j)) * 64 + lane];
            wf1[j] = wfrag[((1 * 4 + kt) * 8 + (w * 2 + j)) * 64 + lane];
        }
#pragma unroll
        for (int mf = 0; mf < 4; mf++)
            xa[mf] = *(const f16x8*)&ht[((mf * 16 + row16) * 128 + kt * 32 + kslot * 8) ^ swz];
#pragma unroll
        for (int mf = 0; mf < 4; mf++)
#pragma unroll
            for (int j = 0; j < 2; j++) {
                acc[0][j][mf] = __builtin_amdgcn_mfma_f32_16x16x32_f16(xa[mf], wf0[j], acc[0][j][mf], 0, 0, 0);
                acc[1][j][mf] = __builtin_amdgcn_mfma_f32_16x16x32_f16(xa[mf], wf1[j], acc[1][j][mf], 0, 0, 0);
            }
    }
#pragma unroll
    for (int j = 0; j < 2; j++) {
        int col = w * 32 + j * 16 + (lane & 15);
        float bias = cb[col];
#pragma unroll
        for (int mf = 0; mf < 4; mf++) {
            int rbase = r0 + mf * 16 + ((lane >> 4) << 2);
#pragma unroll
            for (int q = 0; q < 4; q++) {
                A[(size_t)(rbase + q) * 128 + col] = (f16)(acc[0][j][mf][q] + bias);
                B[(size_t)(rbase + q) * 128 + col] = (f16)acc[1][j][mf][q];
            }
        }
    }
}

// ---------------------------------------------------------------- conv2 + gather2 + pools
// 512 threads / 8 waves; LDS 79.9KB -> 2 blocks/CU = 16 waves/CU.
// Neighbor offsets staged in LDS (nbrL): gather critical path has no global dep.
__global__ __launch_bounds__(512) void k_megac2(
    const f16* __restrict__ A1, const f16* __restrict__ B1,
    const short* __restrict__ nbroff, const f16x8* __restrict__ wfrag,
    const float* __restrict__ cb,
    float* __restrict__ partM1, float* __restrict__ partS1,
    float* __restrict__ partM2, float* __restrict__ partS2) {
    __shared__ char SM[79872];
    char* bw  = SM;                            // B1 window: 128 rows x BWS
    char* b2  = SM;                            // B2: 96 rows x BWS (aliases bw post-gather1)
    f16*  x1t = (f16*)(SM + 34816);            // 96x128 f16 swizzled (24576 B)
    char* a2  = SM + 59392;                    // A2: 64 rows x BWS (17408 B)
    float* redM1 = (float*)(SM + 59392);       // 8x128 f32, aliases a2 (pre-epilogue)
    float* redS1 = (float*)(SM + 63488);
    float* redM2 = (float*)(SM + 34816);       // 8x128 f32, aliases x1t (post-GEMM)
    float* redS2 = (float*)(SM + 38912);
    short* nbrL = (short*)(SM + 76800);        // 96 rows x 16 shorts (3072 B)

    int tid = threadIdx.x;
    int bx = blockIdx.x;
    int r0 = bx * 64;
    int r0loc = (bx & 15) * 64;
    int gbase = r0 - r0loc;                    // graph base row

    // ---- stage B1 window ranks [r0loc-32, r0loc+96): 2048 octets, 4 passes
#pragma unroll
    for (int p = 0; p < 4; p++) {
        int idx = tid + p * 512;               // [0,2048)
        int row = idx >> 4, kq = idx & 15;
        int gl = r0loc - 32 + row;
        f16x8 v;
#pragma unroll
        for (int i = 0; i < 8; i++) v[i] = (f16)0.0f;
        if (gl >= 0 && gl < NPG)
            v = *(const f16x8*)(B1 + (size_t)(gbase + gl) * 128 + kq * 8);
        *(f16x8*)(bw + row * BWS + kq * 16) = v;
    }
    // ---- stage neighbor offsets for ranks [r0loc-16, r0loc+80)
    if (tid < 192) {
        int row = tid >> 1, half = tid & 1;
        int gl = r0loc - 16 + row;
        int4 v = {0, 0, 0, 0};
        if (gl >= 0 && gl < NPG)
            v = ((const int4*)(nbroff + (size_t)(gbase + gl) * KNN))[half];
        ((int4*)nbrL)[tid] = v;
    }
    __syncthreads();

    int w = tid >> 6, lane = tid & 63;         // w in [0,8)
    int rquad = lane >> 4;
    int c0 = (lane & 15) * 8;

    // ---- gather1: x1 for 96 halo rows (12 rows/wave); pool interior [16,80)
    f16x8 pmv;
    float ps[8];
#pragma unroll
    for (int i = 0; i < 8; i++) { pmv[i] = (f16)(-INFINITY); ps[i] = 0.f; }
    // preload offset vectors for this thread's 3 rows (LDS, issue-independent)
    short ow0[16], ow1[16], ow2[16];
    {
        int row0 = w * 12 + 0 * 4 + rquad;
        int row1 = w * 12 + 1 * 4 + rquad;
        int row2 = w * 12 + 2 * 4 + rquad;
        *(int4*)&ow0[0] = ((const int4*)nbrL)[row0 * 2];
        *(int4*)&ow0[8] = ((const int4*)nbrL)[row0 * 2 + 1];
        *(int4*)&ow1[0] = ((const int4*)nbrL)[row1 * 2];
        *(int4*)&ow1[8] = ((const int4*)nbrL)[row1 * 2 + 1];
        *(int4*)&ow2[0] = ((const int4*)nbrL)[row2 * 2];
        *(int4*)&ow2[8] = ((const int4*)nbrL)[row2 * 2 + 1];
    }
#pragma unroll
    for (int rr = 0; rr < 3; rr++) {
        const short* ow = (rr == 0) ? ow0 : (rr == 1) ? ow1 : ow2;
        int row = w * 12 + rr * 4 + rquad;     // [0,96)
        int gl = r0loc - 16 + row;
        f16x8 ou;
#pragma unroll
        for (int i = 0; i < 8; i++) ou[i] = (f16)0.0f;
        if (gl >= 0 && gl < NPG) {
            int grow = gbase + gl;
            f16x8 av = *(const f16x8*)(A1 + (size_t)grow * 128 + c0);
            f16x8 m;
#pragma unroll
            for (int i = 0; i < 8; i++) m[i] = (f16)(-INFINITY);
            const char* base = bw + (row + 16) * BWS + c0 * 2;
#pragma unroll
            for (int q = 0; q < 16; q++) {
                f16x8 bv = *(const f16x8*)(base + (int)ow[q]);
                m = __builtin_elementwise_max(m, bv);
            }
            f16x8 z = {(f16)0, (f16)0, (f16)0, (f16)0, (f16)0, (f16)0, (f16)0, (f16)0};
            ou = __builtin_elementwise_max(av + m, z);
            if ((row >= 16) && (row < 80)) {
                pmv = __builtin_elementwise_max(pmv, ou);
#pragma unroll
                for (int i = 0; i < 8; i++) ps[i] += (float)ou[i];
            }
        }
        int idx = (row * 128 + c0) ^ ((row & 7) << 3);
        *(f16x8*)&x1t[idx] = ou;
    }
    // x1 pool reduce (red1 aliases a2 region; a2 not yet written)
    float pm[8];
#pragma unroll
    for (int i = 0; i < 8; i++) pm[i] = (float)pmv[i];
#pragma unroll
    for (int i = 0; i < 8; i++) {
        pm[i] = fmaxf(pm[i], __shfl_xor(pm[i], 16));
        pm[i] = fmaxf(pm[i], __shfl_xor(pm[i], 32));
        ps[i] += __shfl_xor(ps[i], 16);
        ps[i] += __shfl_xor(ps[i], 32);
    }
    if (rquad == 0) {
#pragma unroll
        for (int i = 0; i < 8; i++) {
            redM1[w * 128 + c0 + i] = pm[i];
            redS1[w * 128 + c0 + i] = ps[i];
        }
    }
    __syncthreads();
    if (tid < 128) {
        float M = -BINF, S = 0.f;
#pragma unroll
        for (int w2 = 0; w2 < 8; w2++) {
            M = fmaxf(M, redM1[w2 * 128 + tid]);
            S += redS1[w2 * 128 + tid];
        }
        partM1[(size_t)bx * 128 + tid] = M;
        partS1[(size_t)bx * 128 + tid] = S;
    }
    __syncthreads();                           // red1 consumed before a2 epilogue writes

    // ---- dual GEMM over 96 rows: each wave one 16-col N-frag
    f32x4 acc[2][6];                           // [out][mf]
#pragma unroll
    for (int o = 0; o < 2; o++)
#pragma unroll
        for (int mf = 0; mf < 6; mf++) acc[o][mf] = (f32x4){0.f, 0.f, 0.f, 0.f};
    int row16 = lane & 15, kslot = lane >> 4;
    int swz = (row16 & 7) << 3;
#pragma unroll 1
    for (int kt = 0; kt < 4; kt++) {
        f16x8 wf0, wf1, xa[6];
        wf0 = wfrag[((0 * 4 + kt) * 8 + w) * 64 + lane];
        wf1 = wfrag[((1 * 4 + kt) * 8 + w) * 64 + lane];
#pragma unroll
        for (int mf = 0; mf < 6; mf++)
            xa[mf] = *(const f16x8*)&x1t[((mf * 16 + row16) * 128 + kt * 32 + kslot * 8) ^ swz];
#pragma unroll
        for (int mf = 0; mf < 6; mf++) {
            acc[0][mf] = __builtin_amdgcn_mfma_f32_16x16x32_f16(xa[mf], wf0, acc[0][mf], 0, 0, 0);
            acc[1][mf] = __builtin_amdgcn_mfma_f32_16x16x32_f16(xa[mf], wf1, acc[1][mf], 0, 0, 0);
        }
    }
    // epilogue -> LDS (B2 all 96 rows; A2 interior 64 rows)
    {
        int col = w * 16 + (lane & 15);
        float bias = cb[col];
#pragma unroll
        for (int mf = 0; mf < 6; mf++) {
            int rloc = mf * 16 + ((lane >> 4) << 2);
#pragma unroll
            for (int q = 0; q < 4; q++) {
                int hrow = rloc + q;           // [0,96)
                *(f16*)(b2 + hrow * BWS + col * 2) = (f16)acc[1][mf][q];
                if (hrow >= 16 && hrow < 80)
                    *(f16*)(a2 + (hrow - 16) * BWS + col * 2) = (f16)(acc[0][mf][q] + bias);
            }
        }
    }
    __syncthreads();                           // GEMM x1t reads done; a2/b2 visible

    // ---- gather2 + pool (interior 64 rows, 8 rows/wave), all from LDS
#pragma unroll
    for (int i = 0; i < 8; i++) { pmv[i] = (f16)(-INFINITY); ps[i] = 0.f; }
    short og0[16], og1[16];
    {
        int rl0 = w * 8 + 0 * 4 + rquad;
        int rl1 = w * 8 + 1 * 4 + rquad;
        *(int4*)&og0[0] = ((const int4*)nbrL)[(rl0 + 16) * 2];
        *(int4*)&og0[8] = ((const int4*)nbrL)[(rl0 + 16) * 2 + 1];
        *(int4*)&og1[0] = ((const int4*)nbrL)[(rl1 + 16) * 2];
        *(int4*)&og1[8] = ((const int4*)nbrL)[(rl1 + 16) * 2 + 1];
    }
#pragma unroll
    for (int rr = 0; rr < 2; rr++) {
        const short* ow = (rr == 0) ? og0 : og1;
        int rl = w * 8 + rr * 4 + rquad;       // [0,64)
        f16x8 av = *(const f16x8*)(a2 + rl * BWS + c0 * 2);
        f16x8 m;
#pragma unroll
        for (int i = 0; i < 8; i++) m[i] = (f16)(-INFINITY);
        const char* base = b2 + (rl + 16) * BWS + c0 * 2;
#pragma unroll
        for (int q = 0; q < 16; q++) {
            f16x8 bv = *(const f16x8*)(base + (int)ow[q]);
            m = __builtin_elementwise_max(m, bv);
        }
        f16x8 z = {(f16)0, (f16)0, (f16)0, (f16)0, (f16)0, (f16)0, (f16)0, (f16)0};
        f16x8 v = __builtin_elementwise_max(av + m, z);
        pmv = __builtin_elementwise_max(pmv, v);
#pragma unroll
        for (int i = 0; i < 8; i++) ps[i] += (float)v[i];
    }
#pragma unroll
    for (int i = 0; i < 8; i++) pm[i] = (float)pmv[i];
#pragma unroll
    for (int i = 0; i < 8; i++) {
        pm[i] = fmaxf(pm[i], __shfl_xor(pm[i], 16));
        pm[i] = fmaxf(pm[i], __shfl_xor(pm[i], 32));
        ps[i] += __shfl_xor(ps[i], 16);
        ps[i] += __shfl_xor(ps[i], 32);
    }
    __syncthreads();                           // x1t fully dead; red2 may overwrite
    if (rquad == 0) {
#pragma unroll
        for (int i = 0; i < 8; i++) {
            redM2[w * 128 + c0 + i] = pm[i];
            redS2[w * 128 + c0 + i] = ps[i];
        }
    }
    __syncthreads();
    if (tid < 128) {
        float M = -BINF, S = 0.f;
#pragma unroll
        for (int w2 = 0; w2 < 8; w2++) {
            M = fmaxf(M, redM2[w2 * 128 + tid]);
            S += redS2[w2 * 128 + tid];
        }
        partM2[(size_t)bx * 128 + tid] = M;
        partS2[(size_t)bx * 128 + tid] = S;
    }
}

// ---------------------------------------------------------------- final head
__global__ __launch_bounds__(256) void k_final(const float* __restrict__ partM1,
                                               const float* __restrict__ partS1,
                                               const float* __restrict__ partM2,
                                               const float* __restrict__ partS2,
                                               const float* __restrict__ fg_lw,
                                               const float* __restrict__ fg_lb,
                                               const float* __restrict__ fg_gw,
                                               const float* __restrict__ fg_gb,
                                               const float* __restrict__ out_w,
                                               const float* __restrict__ out_b,
                                               float* __restrict__ out) {
    __shared__ float pooled[512];
    __shared__ float linv[128], gatev[128];
    __shared__ float gluv[128];
    __shared__ float lg[2];
    int g = blockIdx.x, tid = threadIdx.x;

    const float* pM = (tid < 128) ? partM1 : partM2;
    const float* pS = (tid < 128) ? partS1 : partS2;
    int cc = tid & 127;
    float mx = -BINF, sm = 0.0f;
    for (int ch = 0; ch < 16; ch++) {
        mx = fmaxf(mx, pM[(size_t)(g * 16 + ch) * 128 + cc]);
        sm += pS[(size_t)(g * 16 + ch) * 128 + cc];
    }
    pooled[tid] = mx;
    pooled[256 + tid] = sm * (1.0f / 1024.0f);
    __syncthreads();

    float acc = 0.0f;
    if (tid < 128) {
        for (int k = 0; k < 512; k++) acc = fmaf(pooled[k], fg_lw[k * 128 + tid], acc);
        linv[tid] = acc + fg_lb[tid];
    } else {
        int c = tid - 128;
        for (int k = 0; k < 512; k++) acc = fmaf(pooled[k], fg_gw[k * 128 + c], acc);
        gatev[c] = acc + fg_gb[c];
    }
    __syncthreads();
    if (tid < 128) gluv[tid] = linv[tid] / (1.0f + expf(-gatev[tid]));
    __syncthreads();
    if (tid < 2) {
        float s = out_b[tid];
        for (int c = 0; c < 128; c++) s = fmaf(gluv[c], out_w[c * 2 + tid], s);
        lg[tid] = s;
    }
    __syncthreads();
    if (tid < 2) {
        float m = fmaxf(lg[0], lg[1]);
        float lse = m + logf(expf(lg[0] - m) + expf(lg[1] - m));
        out[g * 2 + tid] = lg[tid] - lse;
    }
}

// ---------------------------------------------------------------- launch
extern "C" void kernel_launch(void* const* d_in, const int* in_sizes, int n_in,
                              void* d_out, int out_size, void* d_ws, size_t ws_size,
                              hipStream_t stream) {
    const float* x     = (const float*)d_in[0];
    const float* te_w  = (const float*)d_in[1];
    const float* te_b  = (const float*)d_in[2];
    const float* ig_lw = (const float*)d_in[3];
    const float* ig_lb = (const float*)d_in[4];
    const float* ig_gw = (const float*)d_in[5];
    const float* ig_gb = (const float*)d_in[6];
    const float* c1_w  = (const float*)d_in[7];
    const float* c1_b  = (const float*)d_in[8];
    const float* c2_w  = (const float*)d_in[9];
    const float* c2_b  = (const float*)d_in[10];
    const float* fg_lw = (const float*)d_in[11];
    const float* fg_lb = (const float*)d_in[12];
    const float* fg_gw = (const float*)d_in[13];
    const float* fg_gb = (const float*)d_in[14];
    const float* out_w = (const float*)d_in[15];
    const float* out_b = (const float*)d_in[16];
    float* out = (float*)d_out;

    // workspace layout (~38 MB)
    char* p = (char*)d_ws;
    const size_t T16 = (size_t)NN * HID * sizeof(f16);   // 16 MB
    f16* A1 = (f16*)p; p += T16;
    f16* B1 = (f16*)p; p += T16;
    int* sidxg = (int*)p;            p += (size_t)NN * 4;
    short* nbroff = (short*)p;       p += (size_t)NN * KNN * 2;
    float* partM1 = (float*)p;       p += (size_t)1024 * 128 * 4;
    float* partS1 = (float*)p;       p += (size_t)1024 * 128 * 4;
    float* partM2 = (float*)p;       p += (size_t)1024 * 128 * 4;
    float* partS2 = (float*)p;       p += (size_t)1024 * 128 * 4;
    f16* gfrag = (f16*)p;            p += 16384 * 2;
    f16* f1 = (f16*)p;               p += 32768 * 2;
    f16* f2 = (f16*)p;               p += 32768 * 2;

    k_topk<<<NG + 80, 1024, 0, stream>>>(x, sidxg, nbroff, ig_lw, ig_gw,
                                         c1_w, c2_w, gfrag, f1, f2);
    k_fuse1<<<NN / 64, 256, 0, stream>>>(x, te_w, te_b, (const f16x8*)gfrag,
                                         ig_lb, ig_gb, sidxg, (const f16x8*)f1,
                                         c1_b, A1, B1);
    k_megac2<<<NN / 64, 512, 0, stream>>>(A1, B1, nbroff, (const f16x8*)f2,
                                          c2_b, partM1, partS1, partM2, partS2);
    k_final<<<NG, 256, 0, stream>>>(partM1, partS1, partM2, partS2,
                                    fg_lw, fg_lb, fg_gw, fg_gb, out_w, out_b, out);
}